// Round 11
// baseline (764.386 us; speedup 1.0000x reference)
//
#include <hip/hip_runtime.h>

#define N_NODES 100000
#define N_EDGES 600000
#define D 128
#define MAXDEG 64
#define OVF_CAP 2048
#define NBK 1563            // ceil(100000/64) buckets of 64 nodes
#define BKCAP 512           // rows per bucket (lambda=384, 6.5 sigma headroom)

typedef __attribute__((ext_vector_type(8))) short bf16x8;
typedef __attribute__((ext_vector_type(4))) float f32x4;
typedef __attribute__((ext_vector_type(2))) float f32x2;

static __device__ inline ushort f2bf(float f) {
    unsigned x = __float_as_uint(f);
    unsigned r = (x + 0x7fffu + ((x >> 16) & 1u)) >> 16;  // RNE
    return (ushort)r;
}
static __device__ inline float bf2f(ushort u) {
    return __uint_as_float((unsigned)u << 16);
}
static __device__ inline ushort4 pack4(f32x4 v) {
    ushort4 u;
    u.x = f2bf(v[0]); u.y = f2bf(v[1]); u.z = f2bf(v[2]); u.w = f2bf(v[3]);
    return u;
}

// ws layout (byte offsets):
//   0         Wfrag   ushort[512*128]       bf16 fused weight, MFMA B-frag order
//   131072    Wcat32  float[512*128]        fp32 fused weight (overflow path)
//   393216    bv      float[128]
//   -- zeroed span [393728, 816640) --
//   393728    cnt     int[100032]           per-node degree counter
//   793856    btail   int[1568]             per-bucket append tails
//   800128    ovfScnt int; 800132 ovfEcnt int  (pad to 800256)
//   800256    ovfS    int[OVF_CAP]
//   808448    ovfE    int[OVF_CAP]
//   -- end zeroed --
//   816640    sendlist int[100032*64]       send idx per node slot (S side)
//   26424832  stag    uint[NBK*BKCAP]       rec&63 per bucket row
//   29625856  easrt16 ushort[NBK*BKCAP*128] appended bf16 ea rows
//
// out[n] = [h[n] | S[n] | deg[n]*h[n] | Ea[n]] @ Wcat + deg[n]*bv + b_upd
// Wfrag[(kb*8+cb)*512 + l*8 + i] = Wcat[kb*32+(l>>4)*8+i][cb*16+(l&15)]
// Wcat rows: 0..127 = Wu1; 128..255 = W1@Wu2; 256..383 = W2@Wu2; 384..511 = W3@Wu2

#define ZERO_INTS ((816640 - 393728) / 4)

__global__ void k_zero(int* __restrict__ z) {
    int i = blockIdx.x * 256 + threadIdx.x;
    if (i < ZERO_INTS) z[i] = 0;
}

__global__ void k_build_w(const float* __restrict__ W_msg,
                          const float* __restrict__ b_msg,
                          const float* __restrict__ W_upd,
                          ushort* __restrict__ Wfrag,
                          float* __restrict__ Wcat32,
                          float* __restrict__ bv)
{
    int gid = blockIdx.x * 256 + threadIdx.x;
    if (gid < 512 * 128) {
        int i = gid & 7;
        int l = (gid >> 3) & 63;
        int fb = gid >> 9;          // kb*8 + cb
        int kb = fb >> 3, cb = fb & 7;
        int k = kb * 32 + ((l >> 4) * 8) + i;
        int j = cb * 16 + (l & 15);
        float acc;
        if (k < 128) {
            acc = W_upd[k * 128 + j];
        } else {
            int r = k - 128;
            acc = 0.f;
            #pragma unroll 4
            for (int dd = 0; dd < 128; ++dd)
                acc += W_msg[r * 128 + dd] * W_upd[(128 + dd) * 128 + j];
        }
        Wfrag[gid] = f2bf(acc);
        Wcat32[k * 128 + j] = acc;
    } else if (gid < 512 * 128 + 128) {
        int j = gid - 512 * 128;
        float acc = 0.f;
        for (int dd = 0; dd < 128; ++dd)
            acc += b_msg[dd] * W_upd[(128 + dd) * 128 + j];
        bv[j] = acc;
    }
}

// Pass A: sequential ea read -> bf16 append into per-bucket streams.
// Also builds sendlist (S side) and both overflow lists.
__global__ __launch_bounds__(256, 8) void k_scat(
    const int* __restrict__ eidx,
    const float* __restrict__ ea,
    int* __restrict__ cnt,
    int* __restrict__ btail,
    int* __restrict__ ovfScnt,
    int* __restrict__ ovfEcnt,
    int* __restrict__ ovfS,
    int* __restrict__ ovfE,
    int* __restrict__ sendlist,
    unsigned* __restrict__ stag,
    ushort* __restrict__ easrt16)
{
    __shared__ int sDst[256];
    const int tid = threadIdx.x;
    const int e0 = blockIdx.x * 256;
    const int e = e0 + tid;

    int dst = -1;
    if (e < N_EDGES) {
        int s = eidx[e];
        int r = eidx[N_EDGES + e];
        int b = r >> 6;
        int slot = atomicAdd(btail + b, 1);
        if (slot < BKCAP) {
            dst = b * BKCAP + slot;
            stag[dst] = (unsigned)(r & 63);
        } else {
            int p = atomicAdd(ovfEcnt, 1);
            if (p < OVF_CAP) ovfE[p] = e;
        }
        int s2 = atomicAdd(cnt + r, 1);
        if (s2 < MAXDEG) {
            sendlist[(size_t)r * MAXDEG + s2] = s;
        } else {
            int p = atomicAdd(ovfScnt, 1);
            if (p < OVF_CAP) ovfS[p] = e;
        }
    }
    sDst[tid] = dst;
    __syncthreads();

    const int lane = tid & 63;
    const int w = tid >> 6;
    for (int i = 0; i < 64; ++i) {
        int d = sDst[w * 64 + i];
        if (d < 0) continue;
        int ee = e0 + w * 64 + i;
        f32x2 v = *(const f32x2*)(ea + (size_t)ee * D + lane * 2);
        unsigned p = (unsigned)f2bf(v[0]) | ((unsigned)f2bf(v[1]) << 16);
        *(unsigned*)(easrt16 + (size_t)d * D + lane * 2) = p;
    }
}

// Pass B: one block per bucket (64 nodes). Ea via LDS fp32 accumulate from the
// bucket's sequential stream; S via cache-served h gather; then MFMA per
// 16-node sub-tile.
__global__ __launch_bounds__(256, 3) void k_nodes(
    const float* __restrict__ h,
    const int* __restrict__ cnt,
    const int* __restrict__ btail,
    const int* __restrict__ sendlist,
    const unsigned* __restrict__ stag,
    const ushort* __restrict__ easrt16,
    const ushort* __restrict__ Wfrag,
    const float* __restrict__ bv,
    const float* __restrict__ b_upd,
    float* __restrict__ out)
{
    __shared__ float EaL[64][128];   // 32 KB fp32 Ea accumulators
    __shared__ ushort Xs[16][520];   // 16.6 KB staged X sub-tile
    __shared__ float degL[16];
    const int tid = threadIdx.x;
    const int lane = tid & 63;
    const int half = lane >> 5;
    const int hl = lane & 31;
    const int wv = tid >> 6;
    const int b = blockIdx.x;
    const int n0 = b * 64;

    // P1: zero EaL
    for (int q = tid; q < 64 * 32; q += 256)
        ((f32x4*)EaL)[q] = (f32x4){0.f, 0.f, 0.f, 0.f};
    __syncthreads();

    // P2: accumulate bucket stream into EaL (sequential 256B rows)
    int nr = btail[b];
    if (nr > BKCAP) nr = BKCAP;
    for (int i = wv; i < nr; i += 4) {
        int rl = (int)(stag[(size_t)b * BKCAP + i] & 63u);
        unsigned p = *(const unsigned*)(easrt16 + ((size_t)b * BKCAP + i) * D + lane * 2);
        atomicAdd(&EaL[rl][lane * 2 + 0], bf2f((ushort)p));
        atomicAdd(&EaL[rl][lane * 2 + 1], bf2f((ushort)(p >> 16)));
    }
    __syncthreads();

    // P3: per 16-node sub-tile: S-gather + stage X + MFMA + epilogue
    for (int st = 0; st < 4; ++st) {
        const int nb = n0 + st * 16 + wv * 4;
        for (int u = 0; u < 4; ++u) {
            const int i = wv * 4 + u;       // row in Xs (0..15)
            const int n = nb + u;
            const bool valid = n < N_NODES;
            const int c = valid ? cnt[n] : 0;
            const int m = c < MAXDEG ? c : MAXDEG;
            int sid = 0;
            if (valid) sid = sendlist[(size_t)n * MAXDEG + lane];

            f32x4 aS = {0.f, 0.f, 0.f, 0.f};
            int t = 0;
            for (; t + 4 <= m; t += 4) {
                int iA = t + half, iB = t + 2 + half;
                int sA = __shfl(sid, iA);
                int sB = __shfl(sid, iB);
                f32x4 a0 = *(const f32x4*)(h + (size_t)sA * D + hl * 4);
                f32x4 a1 = *(const f32x4*)(h + (size_t)sB * D + hl * 4);
                aS += a0 + a1;
            }
            for (; t < m; t += 2) {
                int idx = t + half;
                if (idx < m) {
                    int sA = __shfl(sid, idx);
                    aS += *(const f32x4*)(h + (size_t)sA * D + hl * 4);
                }
            }
            aS[0] += __shfl_xor(aS[0], 32); aS[1] += __shfl_xor(aS[1], 32);
            aS[2] += __shfl_xor(aS[2], 32); aS[3] += __shfl_xor(aS[3], 32);

            const float dv = (float)c;
            f32x4 hn = {0.f, 0.f, 0.f, 0.f};
            if (valid) hn = *(const f32x4*)(h + (size_t)n * D + hl * 4);
            if (half == 0) {
                *(ushort4*)&Xs[i][      hl * 4] = pack4(hn);
                *(ushort4*)&Xs[i][128 + hl * 4] = pack4(aS);
            } else {
                f32x4 dh = {dv * hn[0], dv * hn[1], dv * hn[2], dv * hn[3]};
                f32x4 ev = *(const f32x4*)&EaL[st * 16 + i][hl * 4];
                *(ushort4*)&Xs[i][256 + hl * 4] = pack4(dh);
                *(ushort4*)&Xs[i][384 + hl * 4] = pack4(ev);
            }
            if (lane == 0) degL[i] = dv;
        }
        __syncthreads();

        // MFMA: [16,512]@[512,128]; wave wv does cols 32*wv..+31
        const int arow = lane & 15;
        const int koff = (lane >> 4) * 8;
        f32x4 acc[2] = {};
        for (int kb = 0; kb < 16; ++kb) {
            bf16x8 a = *(const bf16x8*)&Xs[arow][kb * 32 + koff];
            #pragma unroll
            for (int cc = 0; cc < 2; ++cc) {
                int fb = kb * 8 + wv * 2 + cc;
                bf16x8 bfr = *(const bf16x8*)(Wfrag + ((size_t)fb * 64 + lane) * 8);
                acc[cc] = __builtin_amdgcn_mfma_f32_16x16x32_bf16(a, bfr, acc[cc], 0, 0, 0);
            }
        }

        const int r0 = (lane >> 4) * 4;
        #pragma unroll
        for (int cc = 0; cc < 2; ++cc) {
            int col = wv * 32 + cc * 16 + (lane & 15);
            float bvv = bv[col];
            float buv = b_upd[col];
            #pragma unroll
            for (int r = 0; r < 4; ++r) {
                int rl = r0 + r;
                int nOut = n0 + st * 16 + rl;
                if (nOut < N_NODES)
                    out[(size_t)nOut * D + col] = acc[cc][r] + degL[rl] * bvv + buv;
            }
        }
        __syncthreads();   // Xs reused next sub-tile
    }
}

// Overflow edges (expected 0): ovfS adds h_s@(W1@Wu2); ovfE adds ea@(W3@Wu2).
__global__ void k_ovf(const float* __restrict__ h,
                      const int* __restrict__ eidx,
                      const float* __restrict__ ea,
                      const int* __restrict__ ovfScnt,
                      const int* __restrict__ ovfEcnt,
                      const int* __restrict__ ovfS,
                      const int* __restrict__ ovfE,
                      const float* __restrict__ Wcat32,
                      float* __restrict__ out)
{
    int nS = *ovfScnt; if (nS > OVF_CAP) nS = OVF_CAP;
    int nE = *ovfEcnt; if (nE > OVF_CAP) nE = OVF_CAP;
    int tot = nS + nE;
    if (tot <= 0) return;
    int lane = threadIdx.x & 63;
    int w = threadIdx.x >> 6;
    for (int i = w; i < tot; i += 4) {
        bool isS = i < nS;
        int e = isS ? ovfS[i] : ovfE[i - nS];
        int s = eidx[e];
        int r = eidx[N_EDGES + e];
        const float* src = isS ? (h + (size_t)s * D) : (ea + (size_t)e * D);
        int wrow = isS ? 128 : 384;
        float acc0 = 0.f, acc1 = 0.f;
        for (int dd = 0; dd < 128; ++dd) {
            float v = src[dd];
            acc0 += v * Wcat32[(wrow + dd) * 128 + lane * 2];
            acc1 += v * Wcat32[(wrow + dd) * 128 + lane * 2 + 1];
        }
        atomicAdd(out + (size_t)r * D + lane * 2 + 0, acc0);
        atomicAdd(out + (size_t)r * D + lane * 2 + 1, acc1);
    }
}

extern "C" void kernel_launch(void* const* d_in, const int* in_sizes, int n_in,
                              void* d_out, int out_size, void* d_ws, size_t ws_size,
                              hipStream_t stream)
{
    const float* h     = (const float*)d_in[0];
    const int*   eidx  = (const int*)d_in[1];
    const float* eattr = (const float*)d_in[2];
    const float* W_msg = (const float*)d_in[3];
    const float* b_msg = (const float*)d_in[4];
    const float* W_upd = (const float*)d_in[5];
    const float* b_upd = (const float*)d_in[6];
    float* out = (float*)d_out;

    char* base = (char*)d_ws;
    ushort*   Wfrag    = (ushort*)(base);
    float*    Wcat32   = (float*)(base + 131072);
    float*    bv       = (float*)(base + 393216);
    int*      cnt      = (int*)(base + 393728);
    int*      btail    = (int*)(base + 793856);
    int*      ovfScnt  = (int*)(base + 800128);
    int*      ovfEcnt  = (int*)(base + 800132);
    int*      ovfS     = (int*)(base + 800256);
    int*      ovfE     = (int*)(base + 808448);
    int*      sendlist = (int*)(base + 816640);
    unsigned* stag     = (unsigned*)(base + 26424832);
    ushort*   easrt16  = (ushort*)(base + 29625856);

    k_zero<<<(ZERO_INTS + 255) / 256, 256, 0, stream>>>((int*)(base + 393728));
    k_build_w<<<(512 * 128 + 128 + 255) / 256, 256, 0, stream>>>(W_msg, b_msg, W_upd, Wfrag, Wcat32, bv);
    k_scat<<<(N_EDGES + 255) / 256, 256, 0, stream>>>(eidx, eattr, cnt, btail,
                                                      ovfScnt, ovfEcnt, ovfS, ovfE,
                                                      sendlist, stag, easrt16);
    k_nodes<<<NBK, 256, 0, stream>>>(h, cnt, btail, sendlist, stag, easrt16,
                                     Wfrag, bv, b_upd, out);
    k_ovf<<<1, 256, 0, stream>>>(h, eidx, eattr, ovfScnt, ovfEcnt, ovfS, ovfE, Wcat32, out);
}

// Round 12
// 176.403 us; speedup vs baseline: 4.3332x; 4.3332x over previous
//
#include <hip/hip_runtime.h>

#define N_NODES 100000
#define N_EDGES 600000
#define D 128
#define MAXDEG 32
#define OVF_CAP 4096
#define BM 16              // nodes per block

typedef __attribute__((ext_vector_type(8))) short bf16x8;
typedef __attribute__((ext_vector_type(4))) float f32x4;

static __device__ inline ushort f2bf(float f) {
    unsigned x = __float_as_uint(f);
    unsigned r = (x + 0x7fffu + ((x >> 16) & 1u)) >> 16;  // RNE
    return (ushort)r;
}
static __device__ inline f32x4 nt_load4(const float* p) {
    return __builtin_nontemporal_load((const f32x4*)p);
}
static __device__ inline ushort4 pack4(f32x4 v) {
    ushort4 u;
    u.x = f2bf(v[0]); u.y = f2bf(v[1]); u.z = f2bf(v[2]); u.w = f2bf(v[3]);
    return u;
}

// ws layout (byte offsets):
//   0        Wfrag  ushort[512*128]  bf16 fused weight, MFMA B-frag order
//   131072   Wcat32 float[512*128]   fp32 fused weight (overflow path)
//   393216   bv     float[128]
//   393728   cnt    int[N+1] (+pad to 100002)
//   794736   ovf    int[OVF_CAP]
//   811120   elist2 int2[(N+2)*MAXDEG]   (pad: lanes 32..63 prefetch next row)
//
// out[n] = [h[n] | S[n] | deg[n]*h[n] | Ea[n]] @ Wcat + deg[n]*bv + b_upd
// Wfrag[(kb*8+cb)*512 + l*8 + i] = Wcat[kb*32+(l>>4)*8+i][cb*16+(l&15)]
// Wcat rows: 0..127 = Wu1; 128..255 = W1@Wu2; 256..383 = W2@Wu2; 384..511 = W3@Wu2
// bv = b_msg @ Wu2

__global__ void k_zero(int* __restrict__ cnt) {
    int i = blockIdx.x * 256 + threadIdx.x;
    if (i < N_NODES + 1) cnt[i] = 0;
}

__global__ void k_build_w(const float* __restrict__ W_msg,
                          const float* __restrict__ b_msg,
                          const float* __restrict__ W_upd,
                          ushort* __restrict__ Wfrag,
                          float* __restrict__ Wcat32,
                          float* __restrict__ bv)
{
    int gid = blockIdx.x * 256 + threadIdx.x;
    if (gid < 512 * 128) {
        int i = gid & 7;
        int l = (gid >> 3) & 63;
        int fb = gid >> 9;          // kb*8 + cb
        int kb = fb >> 3, cb = fb & 7;
        int k = kb * 32 + ((l >> 4) * 8) + i;
        int j = cb * 16 + (l & 15);
        float acc;
        if (k < 128) {
            acc = W_upd[k * 128 + j];
        } else {
            int r = k - 128;
            acc = 0.f;
            #pragma unroll 4
            for (int dd = 0; dd < 128; ++dd)
                acc += W_msg[r * 128 + dd] * W_upd[(128 + dd) * 128 + j];
        }
        Wfrag[gid] = f2bf(acc);
        Wcat32[k * 128 + j] = acc;
    } else if (gid < 512 * 128 + 128) {
        int j = gid - 512 * 128;
        float acc = 0.f;
        for (int dd = 0; dd < 128; ++dd)
            acc += b_msg[dd] * W_upd[(128 + dd) * 128 + j];
        bv[j] = acc;
    }
}

__global__ void k_bucket(const int* __restrict__ eidx,
                         int* __restrict__ cnt,
                         int* __restrict__ ovf,
                         int2* __restrict__ elist2)
{
    int e = blockIdx.x * 256 + threadIdx.x;
    if (e >= N_EDGES) return;
    int s = eidx[e];
    int r = eidx[N_EDGES + e];
    int slot = atomicAdd(cnt + r, 1);
    if (slot < MAXDEG) {
        elist2[(size_t)r * MAXDEG + slot] = make_int2(e, s);
    } else {
        int p = atomicAdd(cnt + N_NODES, 1);
        if (p < OVF_CAP) ovf[p] = e;
    }
}

// Fused gather + GEMM. 256 thr = 4 waves, BM=16 nodes/block (4 per wave).
// Gather: half-wave per edge — lanes 0-31 load edge t's 512B row as float4,
// lanes 32-63 load edge t+1's row in the SAME instruction.
// Shuffle sources only use lanes 0..31 (m <= MAXDEG = 32).
__global__ __launch_bounds__(256, 8) void k_fused(
    const float* __restrict__ h,
    const float* __restrict__ ea,
    const int* __restrict__ cnt,
    const int2* __restrict__ elist2,
    const ushort* __restrict__ Wfrag,
    const float* __restrict__ bv,
    const float* __restrict__ b_upd,
    float* __restrict__ out)
{
    __shared__ ushort Xs[BM][520];   // bf16 X tile, padded row
    __shared__ float degL[BM];
    const int tid = threadIdx.x;
    const int lane = tid & 63;
    const int half = lane >> 5;      // which edge of the pair
    const int hl = lane & 31;        // float4 column index (cols 4*hl..+3)
    const int wv = tid >> 6;
    const int n0 = blockIdx.x * BM;
    const int nb = n0 + wv * 4;

    // pipeline: preload node 0's metadata (lanes 32-63 land in node+1's row: harmless)
    int2 es = elist2[(size_t)nb * MAXDEG + lane];
    int   c = cnt[nb];

    for (int u = 0; u < 4; ++u) {
        const int i = wv * 4 + u;
        const int n = nb + u;
        int2 es_n; int c_n;
        if (u < 3) {
            es_n = elist2[(size_t)(n + 1) * MAXDEG + lane];
            c_n  = cnt[n + 1];
        }
        const int m = c < MAXDEG ? c : MAXDEG;

        f32x4 aS = {0.f, 0.f, 0.f, 0.f};
        f32x4 aE = {0.f, 0.f, 0.f, 0.f};
        int t = 0;
        for (; t + 4 <= m; t += 4) {          // 4 edges per iter, 4 load insts
            int iA = t + half, iB = t + 2 + half;
            int eA = __shfl(es.x, iA), sA = __shfl(es.y, iA);
            int eB = __shfl(es.x, iB), sB = __shfl(es.y, iB);
            f32x4 a0 = *(const f32x4*)(h + (size_t)sA * D + hl * 4);
            f32x4 b0 = nt_load4(ea + (size_t)eA * D + hl * 4);
            f32x4 a1 = *(const f32x4*)(h + (size_t)sB * D + hl * 4);
            f32x4 b1 = nt_load4(ea + (size_t)eB * D + hl * 4);
            aS += a0 + a1;
            aE += b0 + b1;
        }
        for (; t < m; t += 2) {               // tail: 2 edges per iter, guarded
            int idx = t + half;
            if (idx < m) {
                int eA = __shfl(es.x, idx), sA = __shfl(es.y, idx);
                f32x4 a0 = *(const f32x4*)(h + (size_t)sA * D + hl * 4);
                f32x4 b0 = nt_load4(ea + (size_t)eA * D + hl * 4);
                aS += a0;
                aE += b0;
            }
        }
        // merge even-edge (half 0) and odd-edge (half 1) partial sums
        aS[0] += __shfl_xor(aS[0], 32); aS[1] += __shfl_xor(aS[1], 32);
        aS[2] += __shfl_xor(aS[2], 32); aS[3] += __shfl_xor(aS[3], 32);
        aE[0] += __shfl_xor(aE[0], 32); aE[1] += __shfl_xor(aE[1], 32);
        aE[2] += __shfl_xor(aE[2], 32); aE[3] += __shfl_xor(aE[3], 32);

        const float dv = (float)c;
        f32x4 hn = *(const f32x4*)(h + (size_t)n * D + hl * 4);
        if (half == 0) {
            *(ushort4*)&Xs[i][      hl * 4] = pack4(hn);
            *(ushort4*)&Xs[i][128 + hl * 4] = pack4(aS);
        } else {
            f32x4 dh = {dv * hn[0], dv * hn[1], dv * hn[2], dv * hn[3]};
            *(ushort4*)&Xs[i][256 + hl * 4] = pack4(dh);
            *(ushort4*)&Xs[i][384 + hl * 4] = pack4(aE);
        }
        if (lane == 0) degL[i] = dv;
        es = es_n; c = c_n;
    }
    __syncthreads();

    // MFMA: [16,512]@[512,128]; wave wv does cols 32*wv..+31
    const int arow = lane & 15;
    const int koff = (lane >> 4) * 8;

    f32x4 acc[2] = {};
    for (int kb = 0; kb < 16; ++kb) {
        bf16x8 a = *(const bf16x8*)&Xs[arow][kb * 32 + koff];
        #pragma unroll
        for (int cc = 0; cc < 2; ++cc) {
            int fb = kb * 8 + wv * 2 + cc;
            bf16x8 b = *(const bf16x8*)(Wfrag + ((size_t)fb * 64 + lane) * 8);
            acc[cc] = __builtin_amdgcn_mfma_f32_16x16x32_bf16(a, b, acc[cc], 0, 0, 0);
        }
    }

    const int r0 = (lane >> 4) * 4;
    #pragma unroll
    for (int cc = 0; cc < 2; ++cc) {
        int col = wv * 32 + cc * 16 + (lane & 15);
        float bvv = bv[col];
        float buv = b_upd[col];
        #pragma unroll
        for (int r = 0; r < 4; ++r) {
            int rl = r0 + r;
            out[(size_t)(n0 + rl) * D + col] = acc[cc][r] + degL[rl] * bvv + buv;
        }
    }
}

// Overflow edges (expected 0): add h_s@(W1@Wu2) + ea@(W3@Wu2) into out[rec].
__global__ void k_ovf(const float* __restrict__ h,
                      const int* __restrict__ eidx,
                      const float* __restrict__ ea,
                      const int* __restrict__ cnt,
                      const int* __restrict__ ovf,
                      const float* __restrict__ Wcat32,
                      float* __restrict__ out)
{
    int ncnt = cnt[N_NODES];
    if (ncnt > OVF_CAP) ncnt = OVF_CAP;
    if (ncnt <= 0) return;
    int lane = threadIdx.x & 63;
    int w = threadIdx.x >> 6;
    for (int i = w; i < ncnt; i += 4) {
        int e = ovf[i];
        int s = eidx[e];
        int r = eidx[N_EDGES + e];
        float acc0 = 0.f, acc1 = 0.f;
        for (int dd = 0; dd < 128; ++dd) {
            float hs = h[(size_t)s * D + dd];
            float ev = ea[(size_t)e * D + dd];
            acc0 += hs * Wcat32[(128 + dd) * 128 + lane * 2]     + ev * Wcat32[(384 + dd) * 128 + lane * 2];
            acc1 += hs * Wcat32[(128 + dd) * 128 + lane * 2 + 1] + ev * Wcat32[(384 + dd) * 128 + lane * 2 + 1];
        }
        atomicAdd(out + (size_t)r * D + lane * 2 + 0, acc0);
        atomicAdd(out + (size_t)r * D + lane * 2 + 1, acc1);
    }
}

extern "C" void kernel_launch(void* const* d_in, const int* in_sizes, int n_in,
                              void* d_out, int out_size, void* d_ws, size_t ws_size,
                              hipStream_t stream)
{
    const float* h     = (const float*)d_in[0];
    const int*   eidx  = (const int*)d_in[1];
    const float* eattr = (const float*)d_in[2];
    const float* W_msg = (const float*)d_in[3];
    const float* b_msg = (const float*)d_in[4];
    const float* W_upd = (const float*)d_in[5];
    const float* b_upd = (const float*)d_in[6];
    float* out = (float*)d_out;

    char* base = (char*)d_ws;
    ushort* Wfrag  = (ushort*)(base);
    float*  Wcat32 = (float*)(base + 131072);
    float*  bv     = (float*)(base + 393216);
    int*    cnt    = (int*)(base + 393728);      // N_NODES+1 used (+pad)
    int*    ovf    = (int*)(base + 794736);
    int2*   elist2 = (int2*)(base + 811120);

    k_zero<<<(N_NODES + 1 + 255) / 256, 256, 0, stream>>>(cnt);
    k_build_w<<<(512 * 128 + 128 + 255) / 256, 256, 0, stream>>>(W_msg, b_msg, W_upd, Wfrag, Wcat32, bv);
    k_bucket<<<(N_EDGES + 255) / 256, 256, 0, stream>>>(eidx, cnt, ovf, elist2);
    k_fused<<<N_NODES / BM, 256, 0, stream>>>(h, eattr, cnt, elist2, Wfrag, bv, b_upd, out);
    k_ovf<<<1, 256, 0, stream>>>(h, eidx, eattr, cnt, ovf, Wcat32, out);
}